// Round 6
// baseline (2454.229 us; speedup 1.0000x reference)
//
#include <hip/hip_runtime.h>
#include <stdint.h>

typedef unsigned short u16;
typedef unsigned int   u32;
typedef __attribute__((ext_vector_type(4)))  short s4v;
typedef __attribute__((ext_vector_type(8)))  short s8v;
typedef __attribute__((ext_vector_type(16))) float f16v;

#define JJ 17
#define CC 128
#define BB 7
#define ROWS (BB*JJ)     // 119
#define PP 128
#define XP 132           // u16 pitch for xh/xl planes
#define H1P 130          // f32 pitch for h1 (aliases xh/xl region)
#define NLAYERS 5
#define NT 1024

#define XBUF_BYTES (PP*XP*4)             // 67584 (xh + xl planes; h1 f32 alias uses 66560)
#define WLO_OFF    XBUF_BYTES
#define WLO_BYTES  (2*PP*XP*2)           // 67584
#define ADJS_OFF   (WLO_OFF + WLO_BYTES) // 135168
#define DIAG_OFF   (ADJS_OFF + 1216)     // 136384
#define BIAS_OFF   (DIAG_OFF + 512)      // 136896
#define LDS_BYTES  (BIAS_OFF + 512)      // 137408 -> 1 block/CU, 16 waves

#define MFMA __builtin_amdgcn_mfma_f32_32x32x16_bf16

__device__ __forceinline__ u16 f2bf(float f) {
  u32 u = __float_as_uint(f);
  u += 0x7FFFu + ((u >> 16) & 1u);   // RNE
  return (u16)(u >> 16);
}
__device__ __forceinline__ float bf2f(u16 h) {
  return __uint_as_float(((u32)h) << 16);
}
__device__ __forceinline__ s8v cmb(s4v a, s4v b) {
  s8v r;
  r[0]=a[0]; r[1]=a[1]; r[2]=a[2]; r[3]=a[3];
  r[4]=b[0]; r[5]=b[1]; r[6]=b[2]; r[7]=b[3];
  return r;
}
__device__ __forceinline__ float wred(float v) {
  #pragma unroll
  for (int m = 32; m >= 1; m >>= 1) v += __shfl_xor(v, m, 64);
  return v;
}
__device__ __forceinline__ s8v u4s8(uint4 v) {
  union { uint4 u; s8v s; } c; c.u = v; return c.s;
}

// ---- setup: split W0/W1 into hi/lo bf16 planes, frag layout ws[w][col][k] ----
__global__ void __launch_bounds__(256)
wprep(const float* __restrict__ W0, const float* __restrict__ W1,
      u16* __restrict__ wsH, u16* __restrict__ wsL)
{
  __shared__ float wt[64*130];
  const int w01 = blockIdx.x;
  const float* Wp = w01 ? W1 : W0;
  const int tid = threadIdx.x;
  for (int kh = 0; kh < 2; ++kh) {
    if (kh) __syncthreads();
    #pragma unroll
    for (int i = 0; i < 32; ++i) {
      int idx = tid + i*256;           // [64 kk][128 col] coalesced read
      int kk = idx >> 7, col = idx & 127;
      wt[kk*130 + col] = Wp[(kh*64 + kk)*128 + col];
    }
    __syncthreads();
    #pragma unroll
    for (int i = 0; i < 32; ++i) {
      int idx = tid + i*256;           // [128 col][64 kk] coalesced write
      int col = idx >> 6, kk = idx & 63;
      float v = wt[kk*130 + col];
      u16 h = f2bf(v);
      size_t o = (size_t)(w01*128 + col)*128 + kh*64 + kk;
      wsH[o] = h;
      wsL[o] = f2bf(v - bf2f(h));
    }
  }
}

__global__ void __launch_bounds__(NT, 4)
gconv_fused(const float* __restrict__ x, const float* __restrict__ x0,
            const float* __restrict__ adj, const u16* __restrict__ wsH,
            const u16* __restrict__ wsL, const float* __restrict__ bvec,
            const float* __restrict__ gamma, const float* __restrict__ beta,
            float* __restrict__ out, int totRows)
{
  extern __shared__ char smem[];
  u16*   xh    = (u16*)smem;                   // [PP][XP]
  u16*   xl    = xh + PP*XP;                   // [PP][XP]
  float* h1    = (float*)smem;                 // alias, [PP][H1P] f32
  u16*   wlo   = (u16*)(smem + WLO_OFF);       // [2][PP][XP] (col-major, k-pitched)
  float* adjs  = (float*)(smem + ADJS_OFF);    // [289] 0.8*adj, diag zeroed
  float* diag8 = (float*)(smem + DIAG_OFF);    // [128]
  float* biasl = (float*)(smem + BIAS_OFF);    // [128]

  const int tid  = threadIdx.x;
  const int lane = tid & 63;
  const int wid  = tid >> 6;        // 0..15
  const int wm   = wid >> 2;        // 0..3  M-tile
  const int wn   = wid & 3;         // 0..3  N-tile
  const int g    = lane >> 5;
  const int nl   = lane & 31;
  const int ccol = wn*32 + nl;
  const int arow = wm*32 + nl;
  const int grow0 = blockIdx.x * ROWS;

  // ---- whi straight to regs from precomputed ws (L2-hot)
  s8v whi[2][8];
  #pragma unroll
  for (int w01 = 0; w01 < 2; ++w01) {
    const u16* bh = wsH + (size_t)(w01*128 + ccol)*128;
    #pragma unroll
    for (int ks = 0; ks < 8; ++ks)
      whi[w01][ks] = u4s8(*(const uint4*)&bh[ks*16 + 8*g]);
  }

  // ---- wlo -> LDS (pure copy, no conversion): 32 contiguous u16 per thread
  {
    int el = tid * 32;                 // 0..32767
    int w01 = el >> 14, rem = el & 16383;
    int n = rem >> 7, k0 = rem & 127;
    const u16* src = wsL + el;
    u16* dst = &wlo[(w01*PP + n)*XP + k0];
    #pragma unroll
    for (int c = 0; c < 4; ++c)
      *(uint4*)(dst + c*8) = *(const uint4*)(src + c*8);
  }

  // ---- x -> xh/xl planes (float4 in); pad rows zero
  #pragma unroll
  for (int i = 0; i < 4; ++i) {
    int el4 = tid + i*NT;              // 4096 float4 = 128 rows x 128
    int r = el4 >> 5, c4 = (el4 & 31) << 2;
    float4 v = make_float4(0.f, 0.f, 0.f, 0.f);
    if (r < ROWS && (grow0 + r) < totRows)
      v = *(const float4*)&x[(size_t)(grow0 + r)*CC + c4];
    s4v sh, sl;
    float vv[4] = {v.x, v.y, v.z, v.w};
    #pragma unroll
    for (int e = 0; e < 4; ++e) {
      u16 hh = f2bf(vv[e]);
      sh[e] = (short)hh;
      sl[e] = (short)f2bf(vv[e] - bf2f(hh));
    }
    *(s4v*)&xh[r*XP + c4] = sh;
    *(s4v*)&xl[r*XP + c4] = sl;
  }
  if (tid < JJ*JJ) {
    int j = tid / JJ, k = tid - j*JJ;
    adjs[tid] = (j == k) ? 0.f : 0.8f * adj[tid];
  }
  if (tid >= 512 && tid < 512+PP) {
    int t = tid - 512;
    int j = t % JJ;
    diag8[t] = (t < ROWS) ? 0.8f * adj[j*JJ + j] : 0.f;
  }
  if (tid >= 768 && tid < 768+CC) biasl[tid - 768] = bvec[tid - 768];
  __syncthreads();

  // ================= layer loop =================
  #pragma unroll 1
  for (int layer = 0; layer < NLAYERS; ++layer) {
    f16v acc0, acc1;
    #pragma unroll
    for (int i = 0; i < 16; ++i) { acc0[i] = 0.f; acc1[i] = 0.f; }

    // ---- GEMM: 4x b128 LDS reads + 6 MFMA per ks; no barriers
    #pragma unroll
    for (int ks = 0; ks < 8; ++ks) {
      const int bb0 = ccol*XP + ks*16 + 8*g;
      s8v bl0 = cmb(*(const s4v*)&wlo[bb0], *(const s4v*)&wlo[bb0+4]);
      s8v bl1 = cmb(*(const s4v*)&wlo[PP*XP + bb0], *(const s4v*)&wlo[PP*XP + bb0+4]);
      const int xb = arow*XP + ks*16 + 8*g;
      s8v ah = cmb(*(const s4v*)&xh[xb], *(const s4v*)&xh[xb+4]);
      s8v al = cmb(*(const s4v*)&xl[xb], *(const s4v*)&xl[xb+4]);
      acc0 = MFMA(ah, whi[0][ks], acc0, 0, 0, 0);
      acc0 = MFMA(al, whi[0][ks], acc0, 0, 0, 0);
      acc0 = MFMA(ah, bl0,        acc0, 0, 0, 0);
      acc1 = MFMA(ah, whi[1][ks], acc1, 0, 0, 0);
      acc1 = MFMA(al, whi[1][ks], acc1, 0, 0, 0);
      acc1 = MFMA(ah, bl1,        acc1, 0, 0, 0);
      __builtin_amdgcn_sched_barrier(0);   // cap fragment liveness per K-step
    }
    __syncthreads();               // xh/xl reads done (h1 aliases them)

    // ---- epilogue: acc1 (X@W1) -> h1
    #pragma unroll
    for (int q = 0; q < 16; ++q) {
      int row = wm*32 + (q&3) + 8*(q>>2) + 4*g;
      h1[row*H1P + ccol] = acc1[q];
    }
    __syncthreads();

    // ---- joint mix across 14 waves: elem = wid%7, col-half = wid/7
    if (wid < 14) {
      const int e = wid % 7, half = wid / 7;
      const int rb = e * JJ;
      const int col = half*64 + lane;
      float h[JJ];
      #pragma unroll
      for (int k = 0; k < JJ; ++k)
        h[k] = h1[(rb+k)*H1P + col];
      float m[JJ];
      #pragma unroll 1
      for (int j = 0; j < JJ; ++j) {
        float s = 0.f;
        #pragma unroll
        for (int k = 0; k < JJ; ++k)
          s += adjs[j*JJ + k] * h[k];
        m[j] = s;
      }
      #pragma unroll
      for (int j = 0; j < JJ; ++j)
        h1[(rb+j)*H1P + col] = m[j];
    }
    __syncthreads();

    // ---- combine A: gather into regs (x0 lazy f32, L2/L3-resident)
    float tmp[16];
    #pragma unroll
    for (int q = 0; q < 16; ++q) {
      int row = wm*32 + (q&3) + 8*(q>>2) + 4*g;
      int grow = grow0 + row;
      float x0v = (row < ROWS && grow < totRows) ? x0[(size_t)grow*CC + ccol] : 0.f;
      tmp[q] = 0.2f*x0v + diag8[row]*acc0[q] + h1[row*H1P + ccol] + biasl[ccol];
    }
    __syncthreads();               // h1 reads done before xh/xl overwrite

    // ---- combine B: write new x split
    #pragma unroll
    for (int q = 0; q < 16; ++q) {
      int row = wm*32 + (q&3) + 8*(q>>2) + 4*g;
      u16 hh = f2bf(tmp[q]);
      xh[row*XP + ccol] = hh;
      xl[row*XP + ccol] = f2bf(tmp[q] - bf2f(hh));
    }
    __syncthreads();
  }

  // ---- LayerNorm + store (16 waves)
  float ga = gamma[lane], g2 = gamma[64+lane];
  float ba = beta[lane],  b2 = beta[64+lane];
  #pragma unroll 1
  for (int i = 0; i < 8; ++i) {
    int r = wid + 16*i;              // wave-uniform
    if (r >= ROWS) continue;
    int grow = grow0 + r;
    if (grow >= totRows) continue;
    int xb = r*XP;
    float xa = bf2f(xh[xb+lane])    + bf2f(xl[xb+lane]);
    float xc = bf2f(xh[xb+64+lane]) + bf2f(xl[xb+64+lane]);
    float mu = wred(xa + xc) * (1.f/128.f);
    float da = xa - mu, dc = xc - mu;
    float vs = wred(da*da + dc*dc) * (1.f/128.f);
    float rs = rsqrtf(vs + 1e-10f);
    size_t ob = (size_t)grow*CC;
    out[ob + lane]      = da*rs*ga + ba;
    out[ob + 64 + lane] = dc*rs*g2 + b2;
  }
}

extern "C" void kernel_launch(void* const* d_in, const int* in_sizes, int n_in,
                              void* d_out, int out_size, void* d_ws, size_t ws_size,
                              hipStream_t stream) {
  const float* x   = (const float*)d_in[0];
  const float* x0  = (const float*)d_in[1];
  const float* adj = (const float*)d_in[2];
  const float* W0  = (const float*)d_in[3];
  const float* W1  = (const float*)d_in[4];
  const float* bv  = (const float*)d_in[5];
  const float* ga  = (const float*)d_in[6];
  const float* be  = (const float*)d_in[7];
  u16* wsH = (u16*)d_ws;                    // [2][128][128] bf16 hi
  u16* wsL = wsH + 2*128*128;               // [2][128][128] bf16 lo
  int totRows = in_sizes[0] / CC;
  int nBatch  = totRows / JJ;
  int grid    = (nBatch + BB - 1) / BB;
  wprep<<<dim3(2), dim3(256), 0, stream>>>(W0, W1, wsH, wsL);
  hipFuncSetAttribute((const void*)gconv_fused,
                      hipFuncAttributeMaxDynamicSharedMemorySize, LDS_BYTES);
  gconv_fused<<<dim3(grid), dim3(NT), LDS_BYTES, stream>>>(
      x, x0, adj, wsH, wsL, bv, ga, be, (float*)d_out, totRows);
}

// Round 8
// 1734.043 us; speedup vs baseline: 1.4153x; 1.4153x over previous
//
#include <hip/hip_runtime.h>
#include <stdint.h>

typedef unsigned short u16;
typedef unsigned int   u32;
typedef __attribute__((ext_vector_type(4)))  short s4v;
typedef __attribute__((ext_vector_type(8)))  short s8v;
typedef __attribute__((ext_vector_type(16))) float f16v;
typedef __attribute__((ext_vector_type(2)))  float f2v;

#define JJ 17
#define CC 128
#define BB 7
#define ROWS (BB*JJ)     // 119
#define PP 128
#define XP 136           // u16 pitch: 272B rows -> every frag 16B-aligned (b128)
#define NLAYERS 5
#define NT 512

#define XBUF_BYTES (PP*XP*2*2)           // 69632: xh + xl planes; h1 f32 [128][136] alias
#define WLO_OFF    XBUF_BYTES
#define WLO_BYTES  (2*PP*XP*2)           // 69632
#define ADJS_OFF   (WLO_OFF + WLO_BYTES) // 139264
#define DIAG_OFF   (ADJS_OFF + 1216)     // 140480
#define BIAS_OFF   (DIAG_OFF + 512)      // 140992
#define LDS_BYTES  (BIAS_OFF + 512)      // 141504 -> 1 block/CU

#define MFMA __builtin_amdgcn_mfma_f32_32x32x16_bf16

__device__ __forceinline__ u16 f2bf(float f) {
  u32 u = __float_as_uint(f);
  u += 0x7FFFu + ((u >> 16) & 1u);   // RNE
  return (u16)(u >> 16);
}
__device__ __forceinline__ float bf2f(u16 h) {
  return __uint_as_float(((u32)h) << 16);
}
__device__ __forceinline__ float wred(float v) {
  #pragma unroll
  for (int m = 32; m >= 1; m >>= 1) v += __shfl_xor(v, m, 64);
  return v;
}
__device__ __forceinline__ s8v u4s8(uint4 v) {
  union { uint4 u; s8v s; } c; c.u = v; return c.s;
}

// ---- setup: split W0/W1 into hi/lo bf16 planes, frag layout ws[w][col][k] ----
__global__ void __launch_bounds__(256)
wprep(const float* __restrict__ W0, const float* __restrict__ W1,
      u16* __restrict__ wsH, u16* __restrict__ wsL)
{
  __shared__ float wt[64*130];
  const int w01 = blockIdx.x;
  const float* Wp = w01 ? W1 : W0;
  const int tid = threadIdx.x;
  for (int kh = 0; kh < 2; ++kh) {
    if (kh) __syncthreads();
    #pragma unroll
    for (int i = 0; i < 32; ++i) {
      int idx = tid + i*256;           // [64 kk][128 col] coalesced read
      int kk = idx >> 7, col = idx & 127;
      wt[kk*130 + col] = Wp[(kh*64 + kk)*128 + col];
    }
    __syncthreads();
    #pragma unroll
    for (int i = 0; i < 32; ++i) {
      int idx = tid + i*256;           // [128 col][64 kk] coalesced write
      int col = idx >> 6, kk = idx & 63;
      float v = wt[kk*130 + col];
      u16 h = f2bf(v);
      size_t o = (size_t)(w01*128 + col)*128 + kh*64 + kk;
      wsH[o] = h;
      wsL[o] = f2bf(v - bf2f(h));
    }
  }
}

__global__ void __launch_bounds__(NT, 2)
gconv_fused(const float* __restrict__ x, const float* __restrict__ x0,
            const float* __restrict__ adj, const u16* __restrict__ wsH,
            const u16* __restrict__ wsL, const float* __restrict__ bvec,
            const float* __restrict__ gamma, const float* __restrict__ beta,
            float* __restrict__ out, int totRows)
{
  extern __shared__ char smem[];
  u16*   xh    = (u16*)smem;                   // [PP][XP]
  u16*   xl    = xh + PP*XP;                   // [PP][XP]
  float* h1    = (float*)smem;                 // alias, [PP][XP] f32
  u16*   wlo   = (u16*)(smem + WLO_OFF);       // [2][PP][XP] col-major, k-pitched
  float* adjs  = (float*)(smem + ADJS_OFF);    // [289] 0.8*adj, diag zeroed
  float* diag8 = (float*)(smem + DIAG_OFF);    // [128]
  float* biasl = (float*)(smem + BIAS_OFF);    // [128]

  const int tid  = threadIdx.x;
  const int lane = tid & 63;
  const int wid  = tid >> 6;        // 0..7
  const int wm   = wid >> 2;        // 0..1  (M half)
  const int wn   = wid & 3;         // 0..3  (N tile)
  const int g    = lane >> 5;
  const int nl   = lane & 31;
  const int ccol = wn*32 + nl;
  const int grow0 = blockIdx.x * ROWS;

  // ---- whi straight to regs from precomputed ws (L2-hot)
  s8v whi[2][8];
  #pragma unroll
  for (int w01 = 0; w01 < 2; ++w01) {
    const u16* bh = wsH + (size_t)(w01*128 + ccol)*128;
    #pragma unroll
    for (int ks = 0; ks < 8; ++ks)
      whi[w01][ks] = u4s8(*(const uint4*)&bh[ks*16 + 8*g]);
  }

  // ---- wlo -> LDS (pure 16B copies): 64 contiguous u16 = 8 x uint4 per thread
  {
    int el = tid * 64;                 // 0..32767
    int w01 = el >> 14, rem = el & 16383;
    int col = rem >> 7, k0 = rem & 127;
    const u16* src = wsL + el;
    u16* dst = &wlo[(w01*PP + col)*XP + k0];
    #pragma unroll
    for (int c = 0; c < 8; ++c)        // FIXED: was c<4 (half of wlo left garbage)
      *(uint4*)(dst + c*8) = *(const uint4*)(src + c*8);
  }

  // ---- x -> xh/xl planes (float4 in); pad rows zero
  #pragma unroll
  for (int i = 0; i < 8; ++i) {
    int el4 = tid + i*NT;              // 4096 float4 = 128 rows x 128
    int r = el4 >> 5, c4 = (el4 & 31) << 2;
    float4 v = make_float4(0.f, 0.f, 0.f, 0.f);
    if (r < ROWS && (grow0 + r) < totRows)
      v = *(const float4*)&x[(size_t)(grow0 + r)*CC + c4];
    s4v sh, sl;
    float vv[4] = {v.x, v.y, v.z, v.w};
    #pragma unroll
    for (int e = 0; e < 4; ++e) {
      u16 hh = f2bf(vv[e]);
      sh[e] = (short)hh;
      sl[e] = (short)f2bf(vv[e] - bf2f(hh));
    }
    *(s4v*)&xh[r*XP + c4] = sh;
    *(s4v*)&xl[r*XP + c4] = sl;
  }
  if (tid < JJ*JJ) {
    int j = tid / JJ, k = tid - j*JJ;
    adjs[tid] = (j == k) ? 0.f : 0.8f * adj[tid];
  }
  if (tid < PP) {
    int j = tid % JJ;
    diag8[tid] = (tid < ROWS) ? 0.8f * adj[j*JJ + j] : 0.f;
  }
  if (tid >= 128 && tid < 256) biasl[tid - 128] = bvec[tid - 128];
  __syncthreads();

  const int arow0 = (wm*64 + nl)*XP + 8*g;        // mt=0 row base
  const int arow1 = arow0 + 32*XP;                // mt=1
  const int brow0 = ccol*XP + 8*g;                // wlo w01=0 base
  const int brow1 = brow0 + PP*XP;

  // ================= layer loop =================
  #pragma unroll 1
  for (int layer = 0; layer < NLAYERS; ++layer) {
    f16v acc0[2], acc1[2];
    #pragma unroll
    for (int mt = 0; mt < 2; ++mt)
      #pragma unroll
      for (int i = 0; i < 16; ++i) { acc0[mt][i] = 0.f; acc1[mt][i] = 0.f; }

    // ---- GEMM: software-pipelined (prefetch ks+1 frags before ks MFMAs)
    s8v ah0 = *(const s8v*)&xh[arow0],  al0 = *(const s8v*)&xl[arow0];
    s8v ah1 = *(const s8v*)&xh[arow1],  al1 = *(const s8v*)&xl[arow1];
    s8v b0  = *(const s8v*)&wlo[brow0], b1  = *(const s8v*)&wlo[brow1];
    #pragma unroll
    for (int ks = 0; ks < 8; ++ks) {
      s8v nah0 = ah0, nal0 = al0, nah1 = ah1, nal1 = al1, nb0 = b0, nb1 = b1;
      if (ks < 7) {
        const int o = (ks+1)*16;
        nah0 = *(const s8v*)&xh[arow0 + o];  nal0 = *(const s8v*)&xl[arow0 + o];
        nah1 = *(const s8v*)&xh[arow1 + o];  nal1 = *(const s8v*)&xl[arow1 + o];
        nb0  = *(const s8v*)&wlo[brow0 + o]; nb1  = *(const s8v*)&wlo[brow1 + o];
      }
      acc0[0] = MFMA(ah0, whi[0][ks], acc0[0], 0, 0, 0);
      acc0[0] = MFMA(al0, whi[0][ks], acc0[0], 0, 0, 0);
      acc0[0] = MFMA(ah0, b0,         acc0[0], 0, 0, 0);
      acc1[0] = MFMA(ah0, whi[1][ks], acc1[0], 0, 0, 0);
      acc1[0] = MFMA(al0, whi[1][ks], acc1[0], 0, 0, 0);
      acc1[0] = MFMA(ah0, b1,         acc1[0], 0, 0, 0);
      acc0[1] = MFMA(ah1, whi[0][ks], acc0[1], 0, 0, 0);
      acc0[1] = MFMA(al1, whi[0][ks], acc0[1], 0, 0, 0);
      acc0[1] = MFMA(ah1, b0,         acc0[1], 0, 0, 0);
      acc1[1] = MFMA(ah1, whi[1][ks], acc1[1], 0, 0, 0);
      acc1[1] = MFMA(al1, whi[1][ks], acc1[1], 0, 0, 0);
      acc1[1] = MFMA(ah1, b1,         acc1[1], 0, 0, 0);
      __builtin_amdgcn_sched_barrier(0);   // bound liveness: cur+next only
      ah0 = nah0; al0 = nal0; ah1 = nah1; al1 = nal1; b0 = nb0; b1 = nb1;
    }
    __syncthreads();               // xh/xl reads done (h1 aliases them)

    // ---- epilogue: acc1 (X@W1) -> h1
    #pragma unroll
    for (int mt = 0; mt < 2; ++mt)
      #pragma unroll
      for (int q = 0; q < 16; ++q) {
        int row = wm*64 + mt*32 + (q&3) + 8*(q>>2) + 4*g;
        h1[row*XP + ccol] = acc1[mt][q];
      }
    __syncthreads();

    // ---- joint mix in place (wave wid = batch elem; wave 7 idles)
    if (wid < BB) {
      const int rb = wid * JJ;
      f2v h[JJ];
      #pragma unroll
      for (int k = 0; k < JJ; ++k)
        h[k] = *(const f2v*)&h1[(rb+k)*XP + 2*lane];
      #pragma unroll 2
      for (int j = 0; j < JJ; ++j) {
        f2v m; m.x = 0.f; m.y = 0.f;
        #pragma unroll
        for (int k = 0; k < JJ; ++k) {
          float a = adjs[j*JJ + k];
          m.x += a * h[k].x; m.y += a * h[k].y;
        }
        *(f2v*)&h1[(rb+j)*XP + 2*lane] = m;
      }
    }
    __syncthreads();

    // ---- combine A: gather into regs (x0 lazy f32; block slice L2-resident)
    float tmp[2][16];
    #pragma unroll
    for (int mt = 0; mt < 2; ++mt)
      #pragma unroll
      for (int q = 0; q < 16; ++q) {
        int row = wm*64 + mt*32 + (q&3) + 8*(q>>2) + 4*g;
        int grow = grow0 + row;
        float x0v = (row < ROWS && grow < totRows) ? x0[(size_t)grow*CC + ccol] : 0.f;
        tmp[mt][q] = 0.2f*x0v + diag8[row]*acc0[mt][q] + h1[row*XP + ccol] + biasl[ccol];
      }
    __syncthreads();               // h1 reads done before xh/xl overwrite

    // ---- combine B: write new x split
    #pragma unroll
    for (int mt = 0; mt < 2; ++mt)
      #pragma unroll
      for (int q = 0; q < 16; ++q) {
        int row = wm*64 + mt*32 + (q&3) + 8*(q>>2) + 4*g;
        u16 hh = f2bf(tmp[mt][q]);
        xh[row*XP + ccol] = hh;
        xl[row*XP + ccol] = f2bf(tmp[mt][q] - bf2f(hh));
      }
    __syncthreads();
  }

  // ---- LayerNorm + store
  float ga = gamma[lane], g2 = gamma[64+lane];
  float ba = beta[lane],  b2 = beta[64+lane];
  #pragma unroll 1
  for (int i = 0; i < 16; ++i) {
    int r = wid + 8*i;             // wave-uniform
    if (r >= ROWS) continue;
    int grow = grow0 + r;
    if (grow >= totRows) continue;
    int xb = r*XP;
    float xa = bf2f(xh[xb+lane])    + bf2f(xl[xb+lane]);
    float xc = bf2f(xh[xb+64+lane]) + bf2f(xl[xb+64+lane]);
    float mu = wred(xa + xc) * (1.f/128.f);
    float da = xa - mu, dc = xc - mu;
    float vs = wred(da*da + dc*dc) * (1.f/128.f);
    float rs = rsqrtf(vs + 1e-10f);
    size_t ob = (size_t)grow*CC;
    out[ob + lane]      = da*rs*ga + ba;
    out[ob + 64 + lane] = dc*rs*g2 + b2;
  }
}

extern "C" void kernel_launch(void* const* d_in, const int* in_sizes, int n_in,
                              void* d_out, int out_size, void* d_ws, size_t ws_size,
                              hipStream_t stream) {
  const float* x   = (const float*)d_in[0];
  const float* x0  = (const float*)d_in[1];
  const float* adj = (const float*)d_in[2];
  const float* W0  = (const float*)d_in[3];
  const float* W1  = (const float*)d_in[4];
  const float* bv  = (const float*)d_in[5];
  const float* ga  = (const float*)d_in[6];
  const float* be  = (const float*)d_in[7];
  u16* wsH = (u16*)d_ws;                    // [2][128][128] bf16 hi
  u16* wsL = wsH + 2*128*128;               // [2][128][128] bf16 lo
  int totRows = in_sizes[0] / CC;
  int nBatch  = totRows / JJ;
  int grid    = (nBatch + BB - 1) / BB;
  wprep<<<dim3(2), dim3(256), 0, stream>>>(W0, W1, wsH, wsL);
  hipFuncSetAttribute((const void*)gconv_fused,
                      hipFuncAttributeMaxDynamicSharedMemorySize, LDS_BYTES);
  gconv_fused<<<dim3(grid), dim3(NT), LDS_BYTES, stream>>>(
      x, x0, adj, wsH, wsL, bv, ga, be, (float*)d_out, totRows);
}